// Round 19
// baseline (286.302 us; speedup 1.0000x reference)
//
#include <hip/hip_runtime.h>
#include <math.h>

#define NN    50000
#define NE    1600000
#define INDIM 2000
#define HID   8
#define SLOT  64

// ---------------- bucket fill: rec[d*SLOT+k] = {src, w} ----------------
__global__ __launch_bounds__(512) void k_fill(const int* __restrict__ src,
                                              const int* __restrict__ dst,
                                              const float* __restrict__ ew,
                                              int* __restrict__ cur,
                                              long long* __restrict__ rec, int e) {
    int i = blockIdx.x * 512 + threadIdx.x;
    if (i < e) {
        const int d = dst[i];
        const int k = atomicAdd(&cur[d], 1);
        if (k < SLOT) {
            const long long v = ((long long)__float_as_int(ew[i]) << 32) |
                                (unsigned int)src[i];
            __builtin_nontemporal_store(v, &rec[(size_t)d * SLOT + k]);
        }
    }
}

// ------- gemm + node fused (r14-exact, best measured: 95us) ----------
__global__ __launch_bounds__(512) void k_gemmnode(const float* __restrict__ x,
                                                  const float* __restrict__ W1,
                                                  const int* __restrict__ cur,
                                                  const int2* __restrict__ rec,
                                                  float* __restrict__ dinv,
                                                  float* __restrict__ g1, int n) {
    __shared__ float Wt[HID][INDIM];              // 64000 B -> 2 blocks/CU
    for (int idx = threadIdx.x; idx < INDIM * HID; idx += 512)
        Wt[idx & 7][idx >> 3] = W1[idx];
    __syncthreads();

    const int lane = threadIdx.x & 63;
    const int tile = blockIdx.x * 8 + (threadIdx.x >> 6);
    if (tile >= n / 4) return;
    const int row0 = tile * 4;

    // ---- node part: dinv for rows row0..row0+3 (16 lanes per row) ----
    {
        const int r = lane >> 4, l = lane & 15;
        const int row = row0 + r;
        const int c = min(cur[row], SLOT);
        const int2* __restrict__ bkt = rec + (size_t)row * SLOT;
        float s = 0.f;
        for (int k = l; k < c; k += 16) s += __int_as_float(bkt[k].y);
        s += __shfl_xor(s, 1, 16);
        s += __shfl_xor(s, 2, 16);
        s += __shfl_xor(s, 4, 16);
        s += __shfl_xor(s, 8, 16);
        const float dv = rsqrtf(s + 1.0f);
        if (l == 0) dinv[row] = dv;

        // ---- gemm part (r9 core) ----
        const float* __restrict__ xb = &x[(size_t)row0 * INDIM];
        float acc[32];
#pragma unroll
        for (int v = 0; v < 32; ++v) acc[v] = 0.f;

        const int c0 = lane * 4;
        float4 xc[4], xn[4];
#pragma unroll
        for (int rr = 0; rr < 4; ++rr) {
            xc[rr] = make_float4(0.f, 0.f, 0.f, 0.f);
            if (c0 < INDIM) xc[rr] = *(const float4*)&xb[(size_t)rr * INDIM + c0];
        }

#pragma unroll 1
        for (int k = 0; k < 8; ++k) {
            const int cc = k * 256 + c0;
            const int cn = cc + 256;
#pragma unroll
            for (int rr = 0; rr < 4; ++rr) {
                xn[rr] = make_float4(0.f, 0.f, 0.f, 0.f);
                if (cn < INDIM) xn[rr] = *(const float4*)&xb[(size_t)rr * INDIM + cn];
            }
            if (cc < INDIM) {
#pragma unroll
                for (int j = 0; j < 8; ++j) {
                    const float4 wv = *(const float4*)&Wt[j][cc];
#pragma unroll
                    for (int rr = 0; rr < 4; ++rr)
                        acc[rr * 8 + j] += xc[rr].x * wv.x + xc[rr].y * wv.y +
                                           xc[rr].z * wv.z + xc[rr].w * wv.w;
                }
            }
#pragma unroll
            for (int rr = 0; rr < 4; ++rr) xc[rr] = xn[rr];
        }

        // multiplexed butterfly over 32 values + xor-32 merge (verified r7/r9)
#pragma unroll
        for (int st = 0; st < 5; ++st) {
            const int o = 1 << st;
            const bool hb = (lane & o) != 0;
            const int np = 32 >> (st + 1);
#pragma unroll
            for (int p = 0; p < np; ++p) {
                float v0 = acc[2 * p], v1 = acc[2 * p + 1];
                float send = hb ? v0 : v1;
                float recv = __shfl_xor(send, o);
                acc[p] = (hb ? v1 : v0) + recv;
            }
        }
        acc[0] += __shfl_xor(acc[0], 32);

        const float dvme = __shfl(dv, (lane >> 3) << 4);
        if (lane < 32)
            g1[(size_t)row0 * HID + lane] = dvme * acc[0];
    }
}

// ---------------- gather1: conv1 -> relu -> @W2 -> g2 = dinv * h2 (r9 form) ------
__global__ __launch_bounds__(512) void k_gather1(const int2* __restrict__ rec,
                                                 const int* __restrict__ cur,
                                                 const float* __restrict__ dinv,
                                                 const float* __restrict__ g1,
                                                 const float* __restrict__ b1,
                                                 const float* __restrict__ W2,
                                                 float* __restrict__ g2, int n) {
    __shared__ float sW[HID * HID];
    __shared__ float sb[HID];
    if (threadIdx.x < HID * HID) sW[threadIdx.x] = W2[threadIdx.x];
    if (threadIdx.x < HID) sb[threadIdx.x] = b1[threadIdx.x];
    __syncthreads();

    const int t = blockIdx.x * 512 + threadIdx.x;
    const int i = t >> 3, ch = t & 7;
    if (i >= n) return;

    const int c = min(cur[i], SLOT);
    const int2* __restrict__ bkt = rec + (size_t)i * SLOT;
    int2 rg[8];
#pragma unroll
    for (int j = 0; j < 8; ++j) {
        const int k = ch + 8 * j;
        rg[j] = (k < c) ? bkt[k] : make_int2(i, 0);
    }

    float acc = 0.f;
#pragma unroll
    for (int j = 0; j < 8; ++j) {
        if (8 * j < c) {
#pragma unroll
            for (int u = 0; u < 8; ++u) {
                const int   s = __shfl(rg[j].x, u, 8);
                const float w = __int_as_float(__shfl(rg[j].y, u, 8));
                acc = fmaf(w, g1[(size_t)s * HID + ch], acc);
            }
        }
    }
    acc += g1[(size_t)i * HID + ch];              // self-loop
    const float di = dinv[i];
    const float tv = fmaxf(di * acc + sb[ch], 0.f);
    float h = 0.f;
#pragma unroll
    for (int k = 0; k < HID; ++k)
        h = fmaf(__shfl(tv, k, 8), sW[k * HID + ch], h);
    g2[t] = di * h;
}

// ---------------- gather2: conv2 -> + b2 -> log_softmax -> out (r9 form) ---------
__global__ __launch_bounds__(512) void k_gather2(const int2* __restrict__ rec,
                                                 const int* __restrict__ cur,
                                                 const float* __restrict__ dinv,
                                                 const float* __restrict__ g2,
                                                 const float* __restrict__ b2,
                                                 float* __restrict__ out, int n) {
    __shared__ float sb[HID];
    if (threadIdx.x < HID) sb[threadIdx.x] = b2[threadIdx.x];
    __syncthreads();

    const int t = blockIdx.x * 512 + threadIdx.x;
    const int i = t >> 3, ch = t & 7;
    if (i >= n) return;

    const int c = min(cur[i], SLOT);
    const int2* __restrict__ bkt = rec + (size_t)i * SLOT;
    int2 rg[8];
#pragma unroll
    for (int j = 0; j < 8; ++j) {
        const int k = ch + 8 * j;
        rg[j] = (k < c) ? bkt[k] : make_int2(i, 0);
    }

    float acc = 0.f;
#pragma unroll
    for (int j = 0; j < 8; ++j) {
        if (8 * j < c) {
#pragma unroll
            for (int u = 0; u < 8; ++u) {
                const int   s = __shfl(rg[j].x, u, 8);
                const float w = __int_as_float(__shfl(rg[j].y, u, 8));
                acc = fmaf(w, g2[(size_t)s * HID + ch], acc);
            }
        }
    }
    acc += g2[(size_t)i * HID + ch];              // self-loop
    const float v = dinv[i] * acc + sb[ch];

    float m = v;
    m = fmaxf(m, __shfl_xor(m, 1, 8));
    m = fmaxf(m, __shfl_xor(m, 2, 8));
    m = fmaxf(m, __shfl_xor(m, 4, 8));
    float s = __expf(v - m);
    s += __shfl_xor(s, 1, 8);
    s += __shfl_xor(s, 2, 8);
    s += __shfl_xor(s, 4, 8);
    out[t] = v - (m + __logf(s));
}

// ---- launcher: r14 + GATHER PROBE (both gathers dispatched twice) ----
// Both gathers are idempotent (inputs != outputs). Δ(total vs r14's 250µs)
// = gather1 + gather2 combined time. Decomposes the 155µs "rest".
extern "C" void kernel_launch(void* const* d_in, const int* in_sizes, int n_in,
                              void* d_out, int out_size, void* d_ws, size_t ws_size,
                              hipStream_t stream) {
    const float* x   = (const float*)d_in[0];
    const int*   src = (const int*)d_in[1];
    const int*   dst = (const int*)d_in[2];
    const float* ew  = (const float*)d_in[3];
    const float* W1  = (const float*)d_in[4];
    const float* b1  = (const float*)d_in[5];
    const float* W2  = (const float*)d_in[6];
    const float* b2  = (const float*)d_in[7];
    float* out = (float*)d_out;

    // workspace layout (8-B aligned first)
    long long* rec  = (long long*)d_ws;                 // NN*SLOT int2 (25.6 MB)
    int*       cur  = (int*)(rec + (size_t)NN * SLOT);  // NN
    float*     dinv = (float*)(cur + NN);               // NN
    float*     g1   = dinv + NN;                        // NN*HID
    float*     g2   = g1 + (size_t)NN * HID;            // NN*HID

    const int B = 512;
    const int gE = (NE + B - 1) / B;                    // 3125
    const int g8 = (NN * HID + B - 1) / B;              // 782
    const int gG = (NN / 4 + 7) / 8;                    // 1563

    hipMemsetAsync(cur, 0, NN * sizeof(int), stream);
    k_fill    <<<gE, B, 0, stream>>>(src, dst, ew, cur, rec, NE);
    k_gemmnode<<<gG, B, 0, stream>>>(x, W1, cur, (const int2*)rec, dinv, g1, NN);
    k_gather1 <<<g8, B, 0, stream>>>((const int2*)rec, cur, dinv, g1, b1, W2, g2, NN);
    k_gather1 <<<g8, B, 0, stream>>>((const int2*)rec, cur, dinv, g1, b1, W2, g2, NN);  // probe
    k_gather2 <<<g8, B, 0, stream>>>((const int2*)rec, cur, dinv, g2, b2, out, NN);
    k_gather2 <<<g8, B, 0, stream>>>((const int2*)rec, cur, dinv, g2, b2, out, NN);     // probe
}

// Round 20
// 219.875 us; speedup vs baseline: 1.3021x; 1.3021x over previous
//
#include <hip/hip_runtime.h>
#include <math.h>

#define NN    50000
#define NE    1600000
#define INDIM 2000
#define HID   8
#define SLOT  64
#define CSTR  16   // cur stride: 1 counter per 64B line (kills same-line atomic serialization)

// ---------------- bucket fill: rec[d*SLOT+k] = {src, w} ----------------
// 4 edges/thread grid-strided: 4 independent atomic->store chains in flight.
// Plain (L2-allocating) stores: slots of one dst share lines; L2 absorbs them.
__global__ __launch_bounds__(512) void k_fill(const int* __restrict__ src,
                                              const int* __restrict__ dst,
                                              const float* __restrict__ ew,
                                              int* __restrict__ cur,
                                              long long* __restrict__ rec, int e) {
    const int tid = blockIdx.x * 512 + threadIdx.x;
    const int nth = gridDim.x * 512;
#pragma unroll
    for (int u = 0; u < 4; ++u) {
        const int i = tid + u * nth;
        if (i < e) {
            const int d = dst[i];
            const int k = atomicAdd(&cur[d * CSTR], 1);
            if (k < SLOT)
                rec[(size_t)d * SLOT + k] =
                    ((long long)__float_as_int(ew[i]) << 32) | (unsigned int)src[i];
        }
    }
}

// ------- gemm + node fused (r14-exact core; cur now strided) ----------
__global__ __launch_bounds__(512) void k_gemmnode(const float* __restrict__ x,
                                                  const float* __restrict__ W1,
                                                  const int* __restrict__ cur,
                                                  const int2* __restrict__ rec,
                                                  float* __restrict__ dinv,
                                                  float* __restrict__ g1, int n) {
    __shared__ float Wt[HID][INDIM];              // 64000 B -> 2 blocks/CU
    for (int idx = threadIdx.x; idx < INDIM * HID; idx += 512)
        Wt[idx & 7][idx >> 3] = W1[idx];
    __syncthreads();

    const int lane = threadIdx.x & 63;
    const int tile = blockIdx.x * 8 + (threadIdx.x >> 6);
    if (tile >= n / 4) return;
    const int row0 = tile * 4;

    // ---- node part: dinv for rows row0..row0+3 (16 lanes per row) ----
    {
        const int r = lane >> 4, l = lane & 15;
        const int row = row0 + r;
        const int c = min(cur[row * CSTR], SLOT);
        const int2* __restrict__ bkt = rec + (size_t)row * SLOT;
        float s = 0.f;
        for (int k = l; k < c; k += 16) s += __int_as_float(bkt[k].y);
        s += __shfl_xor(s, 1, 16);
        s += __shfl_xor(s, 2, 16);
        s += __shfl_xor(s, 4, 16);
        s += __shfl_xor(s, 8, 16);
        const float dv = rsqrtf(s + 1.0f);
        if (l == 0) dinv[row] = dv;

        // ---- gemm part (r9 core) ----
        const float* __restrict__ xb = &x[(size_t)row0 * INDIM];
        float acc[32];
#pragma unroll
        for (int v = 0; v < 32; ++v) acc[v] = 0.f;

        const int c0 = lane * 4;
        float4 xc[4], xn[4];
#pragma unroll
        for (int rr = 0; rr < 4; ++rr) {
            xc[rr] = make_float4(0.f, 0.f, 0.f, 0.f);
            if (c0 < INDIM) xc[rr] = *(const float4*)&xb[(size_t)rr * INDIM + c0];
        }

#pragma unroll 1
        for (int k = 0; k < 8; ++k) {
            const int cc = k * 256 + c0;
            const int cn = cc + 256;
#pragma unroll
            for (int rr = 0; rr < 4; ++rr) {
                xn[rr] = make_float4(0.f, 0.f, 0.f, 0.f);
                if (cn < INDIM) xn[rr] = *(const float4*)&xb[(size_t)rr * INDIM + cn];
            }
            if (cc < INDIM) {
#pragma unroll
                for (int j = 0; j < 8; ++j) {
                    const float4 wv = *(const float4*)&Wt[j][cc];
#pragma unroll
                    for (int rr = 0; rr < 4; ++rr)
                        acc[rr * 8 + j] += xc[rr].x * wv.x + xc[rr].y * wv.y +
                                           xc[rr].z * wv.z + xc[rr].w * wv.w;
                }
            }
#pragma unroll
            for (int rr = 0; rr < 4; ++rr) xc[rr] = xn[rr];
        }

        // multiplexed butterfly over 32 values + xor-32 merge (verified r7/r9)
#pragma unroll
        for (int st = 0; st < 5; ++st) {
            const int o = 1 << st;
            const bool hb = (lane & o) != 0;
            const int np = 32 >> (st + 1);
#pragma unroll
            for (int p = 0; p < np; ++p) {
                float v0 = acc[2 * p], v1 = acc[2 * p + 1];
                float send = hb ? v0 : v1;
                float recv = __shfl_xor(send, o);
                acc[p] = (hb ? v1 : v0) + recv;
            }
        }
        acc[0] += __shfl_xor(acc[0], 32);

        const float dvme = __shfl(dv, (lane >> 3) << 4);
        if (lane < 32)
            g1[(size_t)row0 * HID + lane] = dvme * acc[0];
    }
}

// ---------------- gather1: conv1 -> relu -> @W2 -> g2 = dinv * h2 (r9 form) ------
__global__ __launch_bounds__(512) void k_gather1(const int2* __restrict__ rec,
                                                 const int* __restrict__ cur,
                                                 const float* __restrict__ dinv,
                                                 const float* __restrict__ g1,
                                                 const float* __restrict__ b1,
                                                 const float* __restrict__ W2,
                                                 float* __restrict__ g2, int n) {
    __shared__ float sW[HID * HID];
    __shared__ float sb[HID];
    if (threadIdx.x < HID * HID) sW[threadIdx.x] = W2[threadIdx.x];
    if (threadIdx.x < HID) sb[threadIdx.x] = b1[threadIdx.x];
    __syncthreads();

    const int t = blockIdx.x * 512 + threadIdx.x;
    const int i = t >> 3, ch = t & 7;
    if (i >= n) return;

    const int c = min(cur[i * CSTR], SLOT);
    const int2* __restrict__ bkt = rec + (size_t)i * SLOT;
    int2 rg[8];
#pragma unroll
    for (int j = 0; j < 8; ++j) {
        const int k = ch + 8 * j;
        rg[j] = (k < c) ? bkt[k] : make_int2(i, 0);
    }

    float acc = 0.f;
#pragma unroll
    for (int j = 0; j < 8; ++j) {
        if (8 * j < c) {
#pragma unroll
            for (int u = 0; u < 8; ++u) {
                const int   s = __shfl(rg[j].x, u, 8);
                const float w = __int_as_float(__shfl(rg[j].y, u, 8));
                acc = fmaf(w, g1[(size_t)s * HID + ch], acc);
            }
        }
    }
    acc += g1[(size_t)i * HID + ch];              // self-loop
    const float di = dinv[i];
    const float tv = fmaxf(di * acc + sb[ch], 0.f);
    float h = 0.f;
#pragma unroll
    for (int k = 0; k < HID; ++k)
        h = fmaf(__shfl(tv, k, 8), sW[k * HID + ch], h);
    g2[t] = di * h;
}

// ---------------- gather2: conv2 -> + b2 -> log_softmax -> out (r9 form) ---------
__global__ __launch_bounds__(512) void k_gather2(const int2* __restrict__ rec,
                                                 const int* __restrict__ cur,
                                                 const float* __restrict__ dinv,
                                                 const float* __restrict__ g2,
                                                 const float* __restrict__ b2,
                                                 float* __restrict__ out, int n) {
    __shared__ float sb[HID];
    if (threadIdx.x < HID) sb[threadIdx.x] = b2[threadIdx.x];
    __syncthreads();

    const int t = blockIdx.x * 512 + threadIdx.x;
    const int i = t >> 3, ch = t & 7;
    if (i >= n) return;

    const int c = min(cur[i * CSTR], SLOT);
    const int2* __restrict__ bkt = rec + (size_t)i * SLOT;
    int2 rg[8];
#pragma unroll
    for (int j = 0; j < 8; ++j) {
        const int k = ch + 8 * j;
        rg[j] = (k < c) ? bkt[k] : make_int2(i, 0);
    }

    float acc = 0.f;
#pragma unroll
    for (int j = 0; j < 8; ++j) {
        if (8 * j < c) {
#pragma unroll
            for (int u = 0; u < 8; ++u) {
                const int   s = __shfl(rg[j].x, u, 8);
                const float w = __int_as_float(__shfl(rg[j].y, u, 8));
                acc = fmaf(w, g2[(size_t)s * HID + ch], acc);
            }
        }
    }
    acc += g2[(size_t)i * HID + ch];              // self-loop
    const float v = dinv[i] * acc + sb[ch];

    float m = v;
    m = fmaxf(m, __shfl_xor(m, 1, 8));
    m = fmaxf(m, __shfl_xor(m, 2, 8));
    m = fmaxf(m, __shfl_xor(m, 4, 8));
    float s = __expf(v - m);
    s += __shfl_xor(s, 1, 8);
    s += __shfl_xor(s, 2, 8);
    s += __shfl_xor(s, 4, 8);
    out[t] = v - (m + __logf(s));
}

// ---------------- launcher: 5 dispatches (memset + 4 kernels) ----------------
extern "C" void kernel_launch(void* const* d_in, const int* in_sizes, int n_in,
                              void* d_out, int out_size, void* d_ws, size_t ws_size,
                              hipStream_t stream) {
    const float* x   = (const float*)d_in[0];
    const int*   src = (const int*)d_in[1];
    const int*   dst = (const int*)d_in[2];
    const float* ew  = (const float*)d_in[3];
    const float* W1  = (const float*)d_in[4];
    const float* b1  = (const float*)d_in[5];
    const float* W2  = (const float*)d_in[6];
    const float* b2  = (const float*)d_in[7];
    float* out = (float*)d_out;

    // workspace layout (8-B aligned first)
    long long* rec  = (long long*)d_ws;                     // NN*SLOT int2 (25.6 MB)
    int*       cur  = (int*)(rec + (size_t)NN * SLOT);      // NN*CSTR (3.2 MB padded)
    float*     dinv = (float*)(cur + (size_t)NN * CSTR);    // NN
    float*     g1   = dinv + NN;                            // NN*HID
    float*     g2   = g1 + (size_t)NN * HID;                // NN*HID

    const int B = 512;
    const int gE4 = (NE / 4 + B - 1) / B;                   // 782 (4 edges/thread)
    const int g8  = (NN * HID + B - 1) / B;                 // 782
    const int gG  = (NN / 4 + 7) / 8;                       // 1563

    hipMemsetAsync(cur, 0, (size_t)NN * CSTR * sizeof(int), stream);
    k_fill    <<<gE4, B, 0, stream>>>(src, dst, ew, cur, rec, NE);
    k_gemmnode<<<gG,  B, 0, stream>>>(x, W1, cur, (const int2*)rec, dinv, g1, NN);
    k_gather1 <<<g8,  B, 0, stream>>>((const int2*)rec, cur, dinv, g1, b1, W2, g2, NN);
    k_gather2 <<<g8,  B, 0, stream>>>((const int2*)rec, cur, dinv, g2, b2, out, NN);
}

// Round 21
// 218.837 us; speedup vs baseline: 1.3083x; 1.0047x over previous
//
#include <hip/hip_runtime.h>
#include <math.h>

#define NN    50000
#define NE    1600000
#define INDIM 2000
#define HID   8
#define SLOT  64
#define CSTR  16   // cur stride: 1 counter per 64B line (r20-verified)
#define EPT   8    // edges per thread in fill (r21: 4 -> 8, more atomic ILP)

// ---------------- bucket fill: rec[d*SLOT+k] = {src, w} ----------------
// 8 edges/thread grid-strided: 8 independent atomic->store chains in flight.
__global__ __launch_bounds__(512) void k_fill(const int* __restrict__ src,
                                              const int* __restrict__ dst,
                                              const float* __restrict__ ew,
                                              int* __restrict__ cur,
                                              long long* __restrict__ rec, int e) {
    const int tid = blockIdx.x * 512 + threadIdx.x;
    const int nth = gridDim.x * 512;
#pragma unroll
    for (int u = 0; u < EPT; ++u) {
        const int i = tid + u * nth;
        if (i < e) {
            const int d = dst[i];
            const int k = atomicAdd(&cur[d * CSTR], 1);
            if (k < SLOT)
                rec[(size_t)d * SLOT + k] =
                    ((long long)__float_as_int(ew[i]) << 32) | (unsigned int)src[i];
        }
    }
}

// ------- gemm + node fused (r14-exact core; cur strided) ----------
__global__ __launch_bounds__(512) void k_gemmnode(const float* __restrict__ x,
                                                  const float* __restrict__ W1,
                                                  const int* __restrict__ cur,
                                                  const int2* __restrict__ rec,
                                                  float* __restrict__ dinv,
                                                  float* __restrict__ g1, int n) {
    __shared__ float Wt[HID][INDIM];              // 64000 B -> 2 blocks/CU
    for (int idx = threadIdx.x; idx < INDIM * HID; idx += 512)
        Wt[idx & 7][idx >> 3] = W1[idx];
    __syncthreads();

    const int lane = threadIdx.x & 63;
    const int tile = blockIdx.x * 8 + (threadIdx.x >> 6);
    if (tile >= n / 4) return;
    const int row0 = tile * 4;

    // ---- node part: dinv for rows row0..row0+3 (16 lanes per row) ----
    {
        const int r = lane >> 4, l = lane & 15;
        const int row = row0 + r;
        const int c = min(cur[row * CSTR], SLOT);
        const int2* __restrict__ bkt = rec + (size_t)row * SLOT;
        float s = 0.f;
        for (int k = l; k < c; k += 16) s += __int_as_float(bkt[k].y);
        s += __shfl_xor(s, 1, 16);
        s += __shfl_xor(s, 2, 16);
        s += __shfl_xor(s, 4, 16);
        s += __shfl_xor(s, 8, 16);
        const float dv = rsqrtf(s + 1.0f);
        if (l == 0) dinv[row] = dv;

        // ---- gemm part (r9 core) ----
        const float* __restrict__ xb = &x[(size_t)row0 * INDIM];
        float acc[32];
#pragma unroll
        for (int v = 0; v < 32; ++v) acc[v] = 0.f;

        const int c0 = lane * 4;
        float4 xc[4], xn[4];
#pragma unroll
        for (int rr = 0; rr < 4; ++rr) {
            xc[rr] = make_float4(0.f, 0.f, 0.f, 0.f);
            if (c0 < INDIM) xc[rr] = *(const float4*)&xb[(size_t)rr * INDIM + c0];
        }

#pragma unroll 1
        for (int k = 0; k < 8; ++k) {
            const int cc = k * 256 + c0;
            const int cn = cc + 256;
#pragma unroll
            for (int rr = 0; rr < 4; ++rr) {
                xn[rr] = make_float4(0.f, 0.f, 0.f, 0.f);
                if (cn < INDIM) xn[rr] = *(const float4*)&xb[(size_t)rr * INDIM + cn];
            }
            if (cc < INDIM) {
#pragma unroll
                for (int j = 0; j < 8; ++j) {
                    const float4 wv = *(const float4*)&Wt[j][cc];
#pragma unroll
                    for (int rr = 0; rr < 4; ++rr)
                        acc[rr * 8 + j] += xc[rr].x * wv.x + xc[rr].y * wv.y +
                                           xc[rr].z * wv.z + xc[rr].w * wv.w;
                }
            }
#pragma unroll
            for (int rr = 0; rr < 4; ++rr) xc[rr] = xn[rr];
        }

        // multiplexed butterfly over 32 values + xor-32 merge (verified r7/r9)
#pragma unroll
        for (int st = 0; st < 5; ++st) {
            const int o = 1 << st;
            const bool hb = (lane & o) != 0;
            const int np = 32 >> (st + 1);
#pragma unroll
            for (int p = 0; p < np; ++p) {
                float v0 = acc[2 * p], v1 = acc[2 * p + 1];
                float send = hb ? v0 : v1;
                float recv = __shfl_xor(send, o);
                acc[p] = (hb ? v1 : v0) + recv;
            }
        }
        acc[0] += __shfl_xor(acc[0], 32);

        const float dvme = __shfl(dv, (lane >> 3) << 4);
        if (lane < 32)
            g1[(size_t)row0 * HID + lane] = dvme * acc[0];
    }
}

// ---------------- gather1: conv1 -> relu -> @W2 -> g2 = dinv * h2 (r9 form) ------
__global__ __launch_bounds__(512) void k_gather1(const int2* __restrict__ rec,
                                                 const int* __restrict__ cur,
                                                 const float* __restrict__ dinv,
                                                 const float* __restrict__ g1,
                                                 const float* __restrict__ b1,
                                                 const float* __restrict__ W2,
                                                 float* __restrict__ g2, int n) {
    __shared__ float sW[HID * HID];
    __shared__ float sb[HID];
    if (threadIdx.x < HID * HID) sW[threadIdx.x] = W2[threadIdx.x];
    if (threadIdx.x < HID) sb[threadIdx.x] = b1[threadIdx.x];
    __syncthreads();

    const int t = blockIdx.x * 512 + threadIdx.x;
    const int i = t >> 3, ch = t & 7;
    if (i >= n) return;

    const int c = min(cur[i * CSTR], SLOT);
    const int2* __restrict__ bkt = rec + (size_t)i * SLOT;
    int2 rg[8];
#pragma unroll
    for (int j = 0; j < 8; ++j) {
        const int k = ch + 8 * j;
        rg[j] = (k < c) ? bkt[k] : make_int2(i, 0);
    }

    float acc = 0.f;
#pragma unroll
    for (int j = 0; j < 8; ++j) {
        if (8 * j < c) {
#pragma unroll
            for (int u = 0; u < 8; ++u) {
                const int   s = __shfl(rg[j].x, u, 8);
                const float w = __int_as_float(__shfl(rg[j].y, u, 8));
                acc = fmaf(w, g1[(size_t)s * HID + ch], acc);
            }
        }
    }
    acc += g1[(size_t)i * HID + ch];              // self-loop
    const float di = dinv[i];
    const float tv = fmaxf(di * acc + sb[ch], 0.f);
    float h = 0.f;
#pragma unroll
    for (int k = 0; k < HID; ++k)
        h = fmaf(__shfl(tv, k, 8), sW[k * HID + ch], h);
    g2[t] = di * h;
}

// ---------------- gather2: conv2 -> + b2 -> log_softmax -> out (r9 form) ---------
__global__ __launch_bounds__(512) void k_gather2(const int2* __restrict__ rec,
                                                 const int* __restrict__ cur,
                                                 const float* __restrict__ dinv,
                                                 const float* __restrict__ g2,
                                                 const float* __restrict__ b2,
                                                 float* __restrict__ out, int n) {
    __shared__ float sb[HID];
    if (threadIdx.x < HID) sb[threadIdx.x] = b2[threadIdx.x];
    __syncthreads();

    const int t = blockIdx.x * 512 + threadIdx.x;
    const int i = t >> 3, ch = t & 7;
    if (i >= n) return;

    const int c = min(cur[i * CSTR], SLOT);
    const int2* __restrict__ bkt = rec + (size_t)i * SLOT;
    int2 rg[8];
#pragma unroll
    for (int j = 0; j < 8; ++j) {
        const int k = ch + 8 * j;
        rg[j] = (k < c) ? bkt[k] : make_int2(i, 0);
    }

    float acc = 0.f;
#pragma unroll
    for (int j = 0; j < 8; ++j) {
        if (8 * j < c) {
#pragma unroll
            for (int u = 0; u < 8; ++u) {
                const int   s = __shfl(rg[j].x, u, 8);
                const float w = __int_as_float(__shfl(rg[j].y, u, 8));
                acc = fmaf(w, g2[(size_t)s * HID + ch], acc);
            }
        }
    }
    acc += g2[(size_t)i * HID + ch];              // self-loop
    const float v = dinv[i] * acc + sb[ch];

    float m = v;
    m = fmaxf(m, __shfl_xor(m, 1, 8));
    m = fmaxf(m, __shfl_xor(m, 2, 8));
    m = fmaxf(m, __shfl_xor(m, 4, 8));
    float s = __expf(v - m);
    s += __shfl_xor(s, 1, 8);
    s += __shfl_xor(s, 2, 8);
    s += __shfl_xor(s, 4, 8);
    out[t] = v - (m + __logf(s));
}

// ---------------- launcher: 5 dispatches (memset + 4 kernels) ----------------
extern "C" void kernel_launch(void* const* d_in, const int* in_sizes, int n_in,
                              void* d_out, int out_size, void* d_ws, size_t ws_size,
                              hipStream_t stream) {
    const float* x   = (const float*)d_in[0];
    const int*   src = (const int*)d_in[1];
    const int*   dst = (const int*)d_in[2];
    const float* ew  = (const float*)d_in[3];
    const float* W1  = (const float*)d_in[4];
    const float* b1  = (const float*)d_in[5];
    const float* W2  = (const float*)d_in[6];
    const float* b2  = (const float*)d_in[7];
    float* out = (float*)d_out;

    // workspace layout (8-B aligned first)
    long long* rec  = (long long*)d_ws;                     // NN*SLOT int2 (25.6 MB)
    int*       cur  = (int*)(rec + (size_t)NN * SLOT);      // NN*CSTR (3.2 MB padded)
    float*     dinv = (float*)(cur + (size_t)NN * CSTR);    // NN
    float*     g1   = dinv + NN;                            // NN*HID
    float*     g2   = g1 + (size_t)NN * HID;                // NN*HID

    const int B = 512;
    const int gEF = (NE / EPT + B - 1) / B;                 // 391 (8 edges/thread)
    const int g8  = (NN * HID + B - 1) / B;                 // 782
    const int gG  = (NN / 4 + 7) / 8;                       // 1563

    hipMemsetAsync(cur, 0, (size_t)NN * CSTR * sizeof(int), stream);
    k_fill    <<<gEF, B, 0, stream>>>(src, dst, ew, cur, rec, NE);
    k_gemmnode<<<gG,  B, 0, stream>>>(x, W1, cur, (const int2*)rec, dinv, g1, NN);
    k_gather1 <<<g8,  B, 0, stream>>>((const int2*)rec, cur, dinv, g1, b1, W2, g2, NN);
    k_gather2 <<<g8,  B, 0, stream>>>((const int2*)rec, cur, dinv, g2, b2, out, NN);
}

// Round 22
// 170.032 us; speedup vs baseline: 1.6838x; 1.2870x over previous
//
#include <hip/hip_runtime.h>
#include <math.h>

#define NN    50000
#define NE    1600000
#define INDIM 2000
#define HID   8
#define SLOT  64
#define CSTR  16     // cur stride: 1 counter per 64B line (r20-verified)
#define EPT   8      // edges per thread in fill (r21-verified)
#define GF    391    // fill-role blocks (GF*512*EPT >= NE)
#define GTOT  1955   // 391*5: every 5th block is fill, rest gemm (1564 >= 1563 needed)

// ---------------- fused fill + gemm_raw: independent roles, co-resident ----------
// fill role: r21's bucket fill (atomic-latency-bound, ~45MB BW).
// gemm role: r14's gemm core WITHOUT dinv (writes unscaled g1raw; HBM-bound).
// Roles interleaved by blockIdx%5 so both are resident from t=0 and overlap.
__global__ __launch_bounds__(512) void k_fused(const float* __restrict__ x,
                                               const float* __restrict__ W1,
                                               const int* __restrict__ src,
                                               const int* __restrict__ dst,
                                               const float* __restrict__ ew,
                                               int* __restrict__ cur,
                                               long long* __restrict__ rec,
                                               float* __restrict__ g1raw, int n) {
    __shared__ float Wt[HID][INDIM];              // 64000 B (gemm role only)

    if (blockIdx.x % 5 == 0) {
        // ---------------- fill role ----------------
        const int fid = blockIdx.x / 5;           // 0..GF-1
        const int tid = fid * 512 + threadIdx.x;
        const int nth = GF * 512;
#pragma unroll
        for (int u = 0; u < EPT; ++u) {
            const int i = tid + u * nth;
            if (i < NE) {
                const int d = dst[i];
                const int k = atomicAdd(&cur[d * CSTR], 1);
                if (k < SLOT)
                    rec[(size_t)d * SLOT + k] =
                        ((long long)__float_as_int(ew[i]) << 32) | (unsigned int)src[i];
            }
        }
        return;
    }

    // ---------------- gemm role (r14 core, no dinv) ----------------
    const int gid = blockIdx.x - (blockIdx.x / 5) - 1;    // 0..1563
    for (int idx = threadIdx.x; idx < INDIM * HID; idx += 512)
        Wt[idx & 7][idx >> 3] = W1[idx];
    __syncthreads();

    const int lane = threadIdx.x & 63;
    const int tile = gid * 8 + (threadIdx.x >> 6);
    if (tile >= n / 4) return;
    const int row0 = tile * 4;

    const float* __restrict__ xb = &x[(size_t)row0 * INDIM];
    float acc[32];
#pragma unroll
    for (int v = 0; v < 32; ++v) acc[v] = 0.f;

    const int c0 = lane * 4;
    float4 xc[4], xn[4];
#pragma unroll
    for (int rr = 0; rr < 4; ++rr) {
        xc[rr] = make_float4(0.f, 0.f, 0.f, 0.f);
        if (c0 < INDIM) xc[rr] = *(const float4*)&xb[(size_t)rr * INDIM + c0];
    }

#pragma unroll 1
    for (int k = 0; k < 8; ++k) {
        const int cc = k * 256 + c0;
        const int cn = cc + 256;
#pragma unroll
        for (int rr = 0; rr < 4; ++rr) {
            xn[rr] = make_float4(0.f, 0.f, 0.f, 0.f);
            if (cn < INDIM) xn[rr] = *(const float4*)&xb[(size_t)rr * INDIM + cn];
        }
        if (cc < INDIM) {
#pragma unroll
            for (int j = 0; j < 8; ++j) {
                const float4 wv = *(const float4*)&Wt[j][cc];
#pragma unroll
                for (int rr = 0; rr < 4; ++rr)
                    acc[rr * 8 + j] += xc[rr].x * wv.x + xc[rr].y * wv.y +
                                       xc[rr].z * wv.z + xc[rr].w * wv.w;
            }
        }
#pragma unroll
        for (int rr = 0; rr < 4; ++rr) xc[rr] = xn[rr];
    }

    // multiplexed butterfly over 32 values + xor-32 merge (verified r7/r9)
#pragma unroll
    for (int st = 0; st < 5; ++st) {
        const int o = 1 << st;
        const bool hb = (lane & o) != 0;
        const int np = 32 >> (st + 1);
#pragma unroll
        for (int p = 0; p < np; ++p) {
            float v0 = acc[2 * p], v1 = acc[2 * p + 1];
            float send = hb ? v0 : v1;
            float recv = __shfl_xor(send, o);
            acc[p] = (hb ? v1 : v0) + recv;
        }
    }
    acc[0] += __shfl_xor(acc[0], 32);

    if (lane < 32)    // value v=lane: row = row0+(lane>>3), ch = lane&7 — UNSCALED
        g1raw[(size_t)row0 * HID + lane] = acc[0];
}

// ---------------- node pass: dinv from buckets; scale g1 in place ----------------
// 8 lanes/node; butterfly leaves the full sum in all 8 lanes; each lane scales
// its channel. Coalesced read+write of g1 (3.2MB round trip).
__global__ __launch_bounds__(512) void k_node(const int* __restrict__ cur,
                                              const int2* __restrict__ rec,
                                              float* __restrict__ dinv,
                                              float* __restrict__ g1, int n) {
    const int t = blockIdx.x * 512 + threadIdx.x;
    const int i = t >> 3, sl = t & 7;
    if (i >= n) return;
    const int c = min(cur[i * CSTR], SLOT);
    const int2* __restrict__ bkt = rec + (size_t)i * SLOT;
    float s = 0.f;
    for (int k = sl; k < c; k += 8) s += __int_as_float(bkt[k].y);
    s += __shfl_xor(s, 1, 8);
    s += __shfl_xor(s, 2, 8);
    s += __shfl_xor(s, 4, 8);
    const float dv = rsqrtf(s + 1.0f);
    if (sl == 0) dinv[i] = dv;
    g1[t] = dv * g1[t];
}

// ---------------- gather1: conv1 -> relu -> @W2 -> g2 = dinv * h2 (r9 form) ------
__global__ __launch_bounds__(512) void k_gather1(const int2* __restrict__ rec,
                                                 const int* __restrict__ cur,
                                                 const float* __restrict__ dinv,
                                                 const float* __restrict__ g1,
                                                 const float* __restrict__ b1,
                                                 const float* __restrict__ W2,
                                                 float* __restrict__ g2, int n) {
    __shared__ float sW[HID * HID];
    __shared__ float sb[HID];
    if (threadIdx.x < HID * HID) sW[threadIdx.x] = W2[threadIdx.x];
    if (threadIdx.x < HID) sb[threadIdx.x] = b1[threadIdx.x];
    __syncthreads();

    const int t = blockIdx.x * 512 + threadIdx.x;
    const int i = t >> 3, ch = t & 7;
    if (i >= n) return;

    const int c = min(cur[i * CSTR], SLOT);
    const int2* __restrict__ bkt = rec + (size_t)i * SLOT;
    int2 rg[8];
#pragma unroll
    for (int j = 0; j < 8; ++j) {
        const int k = ch + 8 * j;
        rg[j] = (k < c) ? bkt[k] : make_int2(i, 0);
    }

    float acc = 0.f;
#pragma unroll
    for (int j = 0; j < 8; ++j) {
        if (8 * j < c) {
#pragma unroll
            for (int u = 0; u < 8; ++u) {
                const int   s = __shfl(rg[j].x, u, 8);
                const float w = __int_as_float(__shfl(rg[j].y, u, 8));
                acc = fmaf(w, g1[(size_t)s * HID + ch], acc);
            }
        }
    }
    acc += g1[(size_t)i * HID + ch];              // self-loop
    const float di = dinv[i];
    const float tv = fmaxf(di * acc + sb[ch], 0.f);
    float h = 0.f;
#pragma unroll
    for (int k = 0; k < HID; ++k)
        h = fmaf(__shfl(tv, k, 8), sW[k * HID + ch], h);
    g2[t] = di * h;
}

// ---------------- gather2: conv2 -> + b2 -> log_softmax -> out (r9 form) ---------
__global__ __launch_bounds__(512) void k_gather2(const int2* __restrict__ rec,
                                                 const int* __restrict__ cur,
                                                 const float* __restrict__ dinv,
                                                 const float* __restrict__ g2,
                                                 const float* __restrict__ b2,
                                                 float* __restrict__ out, int n) {
    __shared__ float sb[HID];
    if (threadIdx.x < HID) sb[threadIdx.x] = b2[threadIdx.x];
    __syncthreads();

    const int t = blockIdx.x * 512 + threadIdx.x;
    const int i = t >> 3, ch = t & 7;
    if (i >= n) return;

    const int c = min(cur[i * CSTR], SLOT);
    const int2* __restrict__ bkt = rec + (size_t)i * SLOT;
    int2 rg[8];
#pragma unroll
    for (int j = 0; j < 8; ++j) {
        const int k = ch + 8 * j;
        rg[j] = (k < c) ? bkt[k] : make_int2(i, 0);
    }

    float acc = 0.f;
#pragma unroll
    for (int j = 0; j < 8; ++j) {
        if (8 * j < c) {
#pragma unroll
            for (int u = 0; u < 8; ++u) {
                const int   s = __shfl(rg[j].x, u, 8);
                const float w = __int_as_float(__shfl(rg[j].y, u, 8));
                acc = fmaf(w, g2[(size_t)s * HID + ch], acc);
            }
        }
    }
    acc += g2[(size_t)i * HID + ch];              // self-loop
    const float v = dinv[i] * acc + sb[ch];

    float m = v;
    m = fmaxf(m, __shfl_xor(m, 1, 8));
    m = fmaxf(m, __shfl_xor(m, 2, 8));
    m = fmaxf(m, __shfl_xor(m, 4, 8));
    float s = __expf(v - m);
    s += __shfl_xor(s, 1, 8);
    s += __shfl_xor(s, 2, 8);
    s += __shfl_xor(s, 4, 8);
    out[t] = v - (m + __logf(s));
}

// ---------------- launcher: 5 dispatches (memset + 4 kernels) ----------------
extern "C" void kernel_launch(void* const* d_in, const int* in_sizes, int n_in,
                              void* d_out, int out_size, void* d_ws, size_t ws_size,
                              hipStream_t stream) {
    const float* x   = (const float*)d_in[0];
    const int*   src = (const int*)d_in[1];
    const int*   dst = (const int*)d_in[2];
    const float* ew  = (const float*)d_in[3];
    const float* W1  = (const float*)d_in[4];
    const float* b1  = (const float*)d_in[5];
    const float* W2  = (const float*)d_in[6];
    const float* b2  = (const float*)d_in[7];
    float* out = (float*)d_out;

    // workspace layout (8-B aligned first)
    long long* rec  = (long long*)d_ws;                     // NN*SLOT int2 (25.6 MB)
    int*       cur  = (int*)(rec + (size_t)NN * SLOT);      // NN*CSTR (3.2 MB padded)
    float*     dinv = (float*)(cur + (size_t)NN * CSTR);    // NN
    float*     g1   = dinv + NN;                            // NN*HID
    float*     g2   = g1 + (size_t)NN * HID;                // NN*HID

    const int B  = 512;
    const int g8 = (NN * HID + B - 1) / B;                  // 782

    hipMemsetAsync(cur, 0, (size_t)NN * CSTR * sizeof(int), stream);
    k_fused  <<<GTOT, B, 0, stream>>>(x, W1, src, dst, ew, cur, rec, g1, NN);
    k_node   <<<g8,   B, 0, stream>>>(cur, (const int2*)rec, dinv, g1, NN);
    k_gather1<<<g8,   B, 0, stream>>>((const int2*)rec, cur, dinv, g1, b1, W2, g2, NN);
    k_gather2<<<g8,   B, 0, stream>>>((const int2*)rec, cur, dinv, g2, b2, out, NN);
}